// Round 4
// baseline (330.180 us; speedup 1.0000x reference)
//
#include <hip/hip_runtime.h>
#include <math.h>

#define NN 512
#define SD 32
#define HM 64
#define NB 256   // grid blocks = CU count; 1 block/CU (LDS-limited) => co-resident

typedef _Float16 f16x8 __attribute__((ext_vector_type(8)));
typedef float floatx4 __attribute__((ext_vector_type(4)));
typedef unsigned uintx4 __attribute__((ext_vector_type(4)));

// ---- dynamic LDS layout (bytes) ----
#define OFF_HBS   0        // 512 rows x 144 B packed-f16 hip        = 73728
#define OFF_M2L   73728    // 8 waves x 2304 B                       = 18432
#define OFF_MSUM  92160    // 8x32 f32
#define OFF_HPREV 93184    // 2x32 f32
#define OFF_HS    93440    // 2x32 f32
#define OFF_MSG   93696    // 2x32 f32
#define OFF_GI    93952    // 2x96 f32
#define OFF_GH    94720    // 2x96 f32
#define OFF_HJ    95488    // 2 nodes x 128 B packed-f16 hj          = 256
#define OFF_W1T   95744    // 67x65 f32 (pad 65: conflict-free both ways) = 17420
#define OFF_WIH   113168   // 64x97 f32 ([k][r], pad 97)             = 24832
#define OFF_WHH   138000   // 32x97 f32 ([k][r], pad 97)             = 12416
#define LDS_TOTAL 150416   // < 160 KiB/CU

__device__ __forceinline__ float sigmoidf_(float x) {
    return 1.0f / (1.0f + __expf(-x));
}
__device__ __forceinline__ unsigned pkrtz(float a, float b) {
    unsigned r;
    asm("v_cvt_pkrtz_f16_f32 %0, %1, %2" : "=v"(r) : "v"(a), "v"(b));
    return r;
}
__device__ __forceinline__ unsigned pk_add(unsigned a, unsigned b) {
    unsigned r;
    asm("v_pk_add_f16 %0, %1, %2" : "=v"(r) : "v"(a), "v"(b));
    return r;
}
__device__ __forceinline__ unsigned pk_fma(unsigned a, unsigned b, unsigned c) {
    unsigned r;
    asm("v_pk_fma_f16 %0, %1, %2, %3" : "=v"(r) : "v"(a), "v"(b), "v"(c));
    return r;
}
__device__ __forceinline__ unsigned pk_relu(unsigned a) {
    unsigned r, z = 0u;
    asm("v_pk_max_f16 %0, %1, %2" : "=v"(r) : "v"(a), "v"(z));
    return r;
}

// ---------------------------------------------------------------------------
// Grid barrier: packed {gen(hi32), cnt(lo32)} in device memory. RELAXED sc1
// atomics only (L3 point ops) — no agent release/acquire fences (those
// writeback/invalidate whole L2s: the R2 745 us disaster). __syncthreads()
// before arrival drains vmcnt, so this block's sc1 write-through stores are
// at L3 before the counter bumps. Verified correct in R3 (absmax 0.0).
// ---------------------------------------------------------------------------
__device__ __forceinline__ void grid_bar(unsigned long long* pk, unsigned target_gen)
{
    __syncthreads();
    if (threadIdx.x == 0) {
        unsigned long long old =
            __hip_atomic_fetch_add(pk, 1ull, __ATOMIC_RELAXED, __HIP_MEMORY_SCOPE_AGENT);
        if ((unsigned)(old & 0xffffffffull) == (unsigned)(NB - 1))
            __hip_atomic_store(pk, ((unsigned long long)target_gen) << 32,
                               __ATOMIC_RELAXED, __HIP_MEMORY_SCOPE_AGENT);
        while ((unsigned)(__hip_atomic_load(pk, __ATOMIC_RELAXED,
                                            __HIP_MEMORY_SCOPE_AGENT) >> 32) < target_gen)
            __builtin_amdgcn_s_sleep(2);
        (void)__hip_atomic_load(pk, __ATOMIC_ACQUIRE, __HIP_MEMORY_SCOPE_AGENT);
    }
    __syncthreads();
}

// ===========================================================================
// Persistent fused kernel v3. Cross-block state: only hb (5 distinct 64 KB
// buffers, sc1 stores / sc1 L3 reads). hj + h live in LDS. Per-step weights
// (W1T / WihT / WhhT) staged ONCE into LDS with conflict-free padded
// layouts — R3's per-step strided scalar global reads were the 140 us.
// Launched as a NORMAL kernel (graph-capturable); 1 block/CU co-residency.
// ===========================================================================
struct FParams {
    const float *J, *b, *mpW1, *mpb1, *mpW2, *mpb2, *mpW3, *mpb3;
    const float *Wih, *Whh, *bih, *bhh;
    const float *rW1, *rb1, *rW2, *rb2, *rW3, *rb3;
    unsigned *hbg;                 // 5 x 16384 dwords
    unsigned long long *bar;       // packed barrier word
    float *out;
};

__global__ __launch_bounds__(512, 1) void fused3_kernel(FParams p)
{
    extern __shared__ __align__(16) char smem[];
    const int tid  = threadIdx.x;
    const int bid  = blockIdx.x;
    const int lane = tid & 63;
    const int wave = tid >> 6;
    const int nsel = wave >> 2;
    const int nw   = wave & 3;
    const int j    = bid * 2 + nsel;
    const int q    = lane >> 4;
    const int c    = lane & 15;

    char* hbS = smem + OFF_HBS;
    float (*msum)[32]   = (float(*)[32])(smem + OFF_MSUM);
    float (*hPrevS)[32] = (float(*)[32])(smem + OFF_HPREV);
    float (*hS)[32]     = (float(*)[32])(smem + OFF_HS);
    float (*msgS)[32]   = (float(*)[32])(smem + OFF_MSG);
    float (*giS)[96]    = (float(*)[96])(smem + OFF_GI);
    float (*ghS)[96]    = (float(*)[96])(smem + OFF_GH);
    char*  hjL  = smem + OFF_HJ;
    float* w1tL = (float*)(smem + OFF_W1T);   // [d=0..66][cc], pitch 65
    float* wihL = (float*)(smem + OFF_WIH);   // [k=0..63][r], pitch 97
    float* whhL = (float*)(smem + OFF_WHH);   // [k=0..31][r], pitch 97
    char*  m2Lw = smem + OFF_M2L + wave * 2304;

    // ---- one-time: stage per-step weights into LDS (coalesced global reads,
    //      pad-65/97 strides make both LDS writes and reads conflict-free) ----
    for (int n = tid; n < 64 * 67; n += 512) {
        int cc = n / 67, d = n % 67;
        w1tL[d * 65 + cc] = p.mpW1[n];
    }
    for (int n = tid; n < 96 * 64; n += 512)
        wihL[(n & 63) * 97 + (n >> 6)] = p.Wih[n];
    for (int n = tid; n < 96 * 32; n += 512)
        whhL[(n & 31) * 97 + (n >> 5)] = p.Whh[n];

    // ---- invariant per-lane fragment gathers straight from inputs ----
    f16x8 Aw2[2][4], Aw3[2][2];
    #pragma unroll
    for (int f = 0; f < 2; ++f)
        #pragma unroll
        for (int t4 = 0; t4 < 4; ++t4) {
            const float* src = p.mpW2 + (t4 * 16 + c) * 64 + f * 32 + q * 8;
            floatx4 s0 = *(const floatx4*)(src);
            floatx4 s1 = *(const floatx4*)(src + 4);
            uintx4 u;
            u[0] = pkrtz(s0[0], s0[1]); u[1] = pkrtz(s0[2], s0[3]);
            u[2] = pkrtz(s1[0], s1[1]); u[3] = pkrtz(s1[2], s1[3]);
            Aw2[f][t4] = __builtin_bit_cast(f16x8, u);
        }
    #pragma unroll
    for (int f = 0; f < 2; ++f)
        #pragma unroll
        for (int t2 = 0; t2 < 2; ++t2) {
            const float* src = p.mpW3 + (t2 * 16 + c) * 64 + f * 32 + q * 8;
            floatx4 s0 = *(const floatx4*)(src);
            floatx4 s1 = *(const floatx4*)(src + 4);
            uintx4 u;
            u[0] = pkrtz(s0[0], s0[1]); u[1] = pkrtz(s0[2], s0[3]);
            u[2] = pkrtz(s1[0], s1[1]); u[3] = pkrtz(s1[2], s1[3]);
            Aw3[f][t2] = __builtin_bit_cast(f16x8, u);
        }
    uintx4 wja, wjb;
    #pragma unroll
    for (int i = 0; i < 4; ++i) {
        int r0 = q * 8 + 2 * i;
        wja[i] = pkrtz(p.mpW1[r0 * 67 + 64], p.mpW1[(r0 + 1) * 67 + 64]);
        int r1 = r0 + 32;
        wjb[i] = pkrtz(p.mpW1[r1 * 67 + 64], p.mpW1[(r1 + 1) * 67 + 64]);
    }
    floatx4 b2i[4], b3i[2];
    #pragma unroll
    for (int t4 = 0; t4 < 4; ++t4)
        #pragma unroll
        for (int r = 0; r < 4; ++r) b2i[t4][r] = p.mpb2[t4 * 16 + q * 4 + r];
    #pragma unroll
    for (int t2 = 0; t2 < 2; ++t2)
        #pragma unroll
        for (int r = 0; r < 4; ++r) b3i[t2][r] = p.mpb3[t2 * 16 + q * 4 + r];

    // J column j: one-time strided gather (~14 MB HBM chip-wide, hidden)
    const float jA = p.J[((8 * q + nw) * 16 + c) * NN + j];
    const float jB = p.J[((8 * q + 4 + nw) * 16 + c) * NN + j];

    __syncthreads();   // w1tL ready

    // ---- initial projection (h = 0): hb[0] for own 2 nodes + hj -> LDS ----
    if (tid < 128) {
        int node = tid >> 6, cc = tid & 63;
        int jj = bid * 2 + node;
        float bj = p.b[jj];
        float si = bj * w1tL[65 * 65 + cc];
        float sj = bj * w1tL[66 * 65 + cc] + p.mpb1[cc];
        float sip = __shfl(si, lane ^ 1);
        float sjp = __shfl(sj, lane ^ 1);
        if (!(cc & 1)) {
            __hip_atomic_store(&p.hbg[jj * 32 + (cc >> 1)], pkrtz(si, sip),
                               __ATOMIC_RELAXED, __HIP_MEMORY_SCOPE_AGENT);
            *(unsigned*)(hjL + node * 128 + (cc >> 1) * 4) = pkrtz(sj, sjp);
        }
    }
    grid_bar(p.bar, 1);

    // ---------------- 5 fused steps ----------------
    #pragma unroll 1
    for (int t = 0; t < 5; ++t) {
        // ---- stage hb[t] (64 KB) -> LDS via sc1 L3 reads ----
        {
            const unsigned long long* gq =
                (const unsigned long long*)(p.hbg + t * 16384);
            uintx4 cr[8];
            #pragma unroll
            for (int k = 0; k < 8; ++k) {
                unsigned long long lo = __hip_atomic_load(gq + (k * 512 + tid) * 2,
                    __ATOMIC_RELAXED, __HIP_MEMORY_SCOPE_AGENT);
                unsigned long long hi = __hip_atomic_load(gq + (k * 512 + tid) * 2 + 1,
                    __ATOMIC_RELAXED, __HIP_MEMORY_SCOPE_AGENT);
                cr[k][0] = (unsigned)lo; cr[k][1] = (unsigned)(lo >> 32);
                cr[k][2] = (unsigned)hi; cr[k][3] = (unsigned)(hi >> 32);
            }
            #pragma unroll
            for (int k = 0; k < 8; ++k) {
                int row = k * 64 + (tid >> 3);
                *(uintx4*)(hbS + row * 144 + (tid & 7) * 16) = cr[k];
            }
        }
        uintx4 hja = *(const uintx4*)(hjL + nsel * 128 + q * 16);
        uintx4 hjb = *(const uintx4*)(hjL + nsel * 128 + 64 + q * 16);
        __syncthreads();

        float accf[2][4];
        #pragma unroll
        for (int t2 = 0; t2 < 2; ++t2)
            #pragma unroll
            for (int r = 0; r < 4; ++r) accf[t2][r] = 0.0f;

        auto edge_group = [&](int G, float Jv) {
            const char* rb = hbS + (G * 16 + c) * 144;
            uintx4 vlo = *(const uintx4*)(rb + q * 16);
            uintx4 vhi = *(const uintx4*)(rb + 64 + q * 16);
            const unsigned Jp = pkrtz(Jv, Jv);

            uintx4 a0u, a1u;
            #pragma unroll
            for (int i = 0; i < 4; ++i) {
                a0u[i] = pk_relu(pk_fma(Jp, wja[i], pk_add(vlo[i], hja[i])));
                a1u[i] = pk_relu(pk_fma(Jp, wjb[i], pk_add(vhi[i], hjb[i])));
            }
            f16x8 B0 = __builtin_bit_cast(f16x8, a0u);
            f16x8 B1 = __builtin_bit_cast(f16x8, a1u);

            floatx4 c1[4];
            #pragma unroll
            for (int t4 = 0; t4 < 4; ++t4) {
                c1[t4] = __builtin_amdgcn_mfma_f32_16x16x32_f16(Aw2[0][t4], B0, b2i[t4], 0, 0, 0);
                c1[t4] = __builtin_amdgcn_mfma_f32_16x16x32_f16(Aw2[1][t4], B1, c1[t4], 0, 0, 0);
            }
            #pragma unroll
            for (int t4 = 0; t4 < 4; ++t4) {
                unsigned p0 = pkrtz(fmaxf(c1[t4][0], 0.f), fmaxf(c1[t4][1], 0.f));
                unsigned p1 = pkrtz(fmaxf(c1[t4][2], 0.f), fmaxf(c1[t4][3], 0.f));
                *(uint2*)(m2Lw + c * 144 + t4 * 32 + q * 8) = make_uint2(p0, p1);
            }
            uintx4 rlo = *(const uintx4*)(m2Lw + c * 144 + q * 16);
            uintx4 rhi = *(const uintx4*)(m2Lw + c * 144 + 64 + q * 16);
            f16x8 B2lo = __builtin_bit_cast(f16x8, rlo);
            f16x8 B2hi = __builtin_bit_cast(f16x8, rhi);

            floatx4 c2[2];
            #pragma unroll
            for (int t2 = 0; t2 < 2; ++t2) {
                c2[t2] = __builtin_amdgcn_mfma_f32_16x16x32_f16(Aw3[0][t2], B2lo, b3i[t2], 0, 0, 0);
                c2[t2] = __builtin_amdgcn_mfma_f32_16x16x32_f16(Aw3[1][t2], B2hi, c2[t2], 0, 0, 0);
            }
            #pragma unroll
            for (int t2 = 0; t2 < 2; ++t2)
                #pragma unroll
                for (int r = 0; r < 4; ++r)
                    accf[t2][r] += fmaxf(c2[t2][r], 0.0f);
        };

        #pragma unroll
        for (int k = 0; k < 4; ++k) {
            edge_group(8 * k + nw,     __shfl(jA, k * 16 + c));
            edge_group(8 * k + 4 + nw, __shfl(jB, k * 16 + c));
        }

        #pragma unroll
        for (int m = 1; m < 16; m <<= 1)
            #pragma unroll
            for (int t2 = 0; t2 < 2; ++t2)
                #pragma unroll
                for (int r = 0; r < 4; ++r)
                    accf[t2][r] += __shfl_xor(accf[t2][r], m);
        if (c == 0) {
            #pragma unroll
            for (int t2 = 0; t2 < 2; ++t2)
                #pragma unroll
                for (int r = 0; r < 4; ++r)
                    msum[wave][t2 * 16 + q * 4 + r] = accf[t2][r];
        }
        __syncthreads();

        if (tid < 64) {
            int node = tid >> 5, d = tid & 31;
            msgS[node][d] = msum[node * 4 + 0][d] + msum[node * 4 + 1][d] +
                            msum[node * 4 + 2][d] + msum[node * 4 + 3][d];
        }
        __syncthreads();

        if (tid < 192) {
            int node = tid / 96, r = tid % 96;
            float a  = p.bih[r];
            float bb = p.bhh[r];
            if (t != 0) {
                #pragma unroll
                for (int k = 0; k < 32; ++k) {
                    float hv = hPrevS[node][k];
                    a  = fmaf(hv, wihL[k * 97 + r], a);
                    bb = fmaf(hv, whhL[k * 97 + r], bb);
                }
            }
            #pragma unroll
            for (int k = 0; k < 32; ++k)
                a = fmaf(msgS[node][k], wihL[(32 + k) * 97 + r], a);
            giS[node][r] = a; ghS[node][r] = bb;
        }
        __syncthreads();

        if (tid < 64) {
            int node = tid >> 5, d = tid & 31;
            float r  = sigmoidf_(giS[node][d] + ghS[node][d]);
            float z  = sigmoidf_(giS[node][32 + d] + ghS[node][32 + d]);
            float ng = tanhf(giS[node][64 + d] + r * ghS[node][64 + d]);
            float hold = (t == 0) ? 0.0f : hPrevS[node][d];
            float hv = (1.0f - z) * ng + z * hold;
            hS[node][d] = hv;
            hPrevS[node][d] = hv;
        }
        __syncthreads();

        if (t < 4) {
            if (tid < 128) {
                int node = tid >> 6, cc = tid & 63;
                int jj = bid * 2 + node;
                float bj = p.b[jj];
                float si = bj * w1tL[65 * 65 + cc];
                float sj = bj * w1tL[66 * 65 + cc] + p.mpb1[cc];
                #pragma unroll
                for (int d = 0; d < 32; ++d) {
                    float hv = hS[node][d];
                    si = fmaf(hv, w1tL[d * 65 + cc], si);
                    sj = fmaf(hv, w1tL[(32 + d) * 65 + cc], sj);
                }
                float sip = __shfl(si, lane ^ 1);
                float sjp = __shfl(sj, lane ^ 1);
                if (!(cc & 1)) {
                    __hip_atomic_store(&p.hbg[(t + 1) * 16384 + jj * 32 + (cc >> 1)],
                                       pkrtz(si, sip),
                                       __ATOMIC_RELAXED, __HIP_MEMORY_SCOPE_AGENT);
                    *(unsigned*)(hjL + node * 128 + (cc >> 1) * 4) = pkrtz(sj, sjp);
                }
            }
            grid_bar(p.bar, (unsigned)(t + 2));
        } else {
            if (wave < 2) {
                int node = wave;
                int jj = bid * 2 + node;
                float y1 = p.rb1[lane];
                const floatx4* w1p = (const floatx4*)(p.rW1 + lane * 32);
                #pragma unroll
                for (int kk = 0; kk < 8; ++kk) {
                    floatx4 v = w1p[kk];
                    #pragma unroll
                    for (int i = 0; i < 4; ++i)
                        y1 = fmaf(hS[node][kk * 4 + i], v[i], y1);
                }
                y1 = fmaxf(y1, 0.0f);
                float y2 = p.rb2[lane];
                const floatx4* w2p = (const floatx4*)(p.rW2 + lane * 64);
                #pragma unroll
                for (int kk = 0; kk < 16; ++kk) {
                    floatx4 v = w2p[kk];
                    #pragma unroll
                    for (int i = 0; i < 4; ++i)
                        y2 = fmaf(__shfl(y1, kk * 4 + i), v[i], y2);
                }
                y2 = fmaxf(y2, 0.0f);
                float y3 = (lane < 2) ? p.rb3[lane] : 0.0f;
                #pragma unroll
                for (int k = 0; k < 64; ++k) {
                    float v = __shfl(y2, k);
                    if (lane < 2) y3 = fmaf(v, p.rW3[lane * 64 + k], y3);
                }
                if (lane < 2) p.out[jj * 2 + lane] = sigmoidf_(y3);
            }
        }
    }
}

// ---------------------------------------------------------------------------
extern "C" void kernel_launch(void* const* d_in, const int* in_sizes, int n_in,
                              void* d_out, int out_size, void* d_ws, size_t ws_size,
                              hipStream_t stream)
{
    float* ws = (float*)d_ws;

    const float* J    = (const float*)d_in[0];
    const float* b    = (const float*)d_in[1];
    const float* mpW1 = (const float*)d_in[2];
    const float* mpb1 = (const float*)d_in[3];
    const float* mpW2 = (const float*)d_in[4];
    const float* mpb2 = (const float*)d_in[5];
    const float* mpW3 = (const float*)d_in[6];
    const float* mpb3 = (const float*)d_in[7];
    const float* Wih  = (const float*)d_in[8];
    const float* Whh  = (const float*)d_in[9];
    const float* bih  = (const float*)d_in[10];
    const float* bhh  = (const float*)d_in[11];
    const float* rW1  = (const float*)d_in[12];
    const float* rb1  = (const float*)d_in[13];
    const float* rW2  = (const float*)d_in[14];
    const float* rb2  = (const float*)d_in[15];
    const float* rW3  = (const float*)d_in[16];
    const float* rb3  = (const float*)d_in[17];

    // hb ping-pong chain + barrier word, 8 MB into the workspace
    unsigned* hbg = (unsigned*)(ws + 2097152);              // 5 x 16384 dwords
    unsigned long long* bar = (unsigned long long*)(ws + 2097152 + 5 * 16384);

    (void)hipFuncSetAttribute((const void*)fused3_kernel,
                              hipFuncAttributeMaxDynamicSharedMemorySize, LDS_TOTAL);

    FParams fp;
    fp.J = J; fp.b = b; fp.mpW1 = mpW1; fp.mpb1 = mpb1; fp.mpW2 = mpW2;
    fp.mpb2 = mpb2; fp.mpW3 = mpW3; fp.mpb3 = mpb3;
    fp.Wih = Wih; fp.Whh = Whh; fp.bih = bih; fp.bhh = bhh;
    fp.rW1 = rW1; fp.rb1 = rb1; fp.rW2 = rW2; fp.rb2 = rb2; fp.rW3 = rW3; fp.rb3 = rb3;
    fp.hbg = hbg; fp.bar = bar;
    fp.out = (float*)d_out;

    (void)hipMemsetAsync((void*)bar, 0, 128, stream);

    // Normal launch (graph-capturable). 256 blocks x 1 block/CU => co-resident;
    // the L3-scope spin barrier inside needs no cooperative-launch support.
    fused3_kernel<<<dim3(NB), dim3(512), LDS_TOTAL, stream>>>(fp);
}

// Round 5
// 250.364 us; speedup vs baseline: 1.3188x; 1.3188x over previous
//
#include <hip/hip_runtime.h>
#include <math.h>

#define NN 512
#define SD 32
#define HM 64
#define NB 256   // grid blocks = CU count; 1 block/CU (LDS-limited) => co-resident (proven R4)

typedef _Float16 f16x8 __attribute__((ext_vector_type(8)));
typedef float floatx4 __attribute__((ext_vector_type(4)));
typedef unsigned uintx4 __attribute__((ext_vector_type(4)));

// ---- dynamic LDS layout (bytes) ----
#define OFF_HBS   0        // 512 rows x 144 B packed-f16 hip        = 73728
#define OFF_M2L   73728    // 8 waves x 2304 B                       = 18432
#define OFF_MSUM  92160    // 8x32 f32
#define OFF_HPREV 93184    // 2x32 f32
#define OFF_HS    93440    // 2x32 f32
#define OFF_MSG   93696    // 2x32 f32
#define OFF_GI    93952    // 2x96 f32
#define OFF_GH    94720    // 2x96 f32
#define OFF_HJ    95488    // 2 nodes x 128 B packed-f16 hj          = 256
#define OFF_W1T   95744    // 67x65 f32 (pad 65)                     = 17420
#define OFF_WIH   113168   // 64x97 f32 ([k][r], pad 97)             = 24832
#define OFF_WHH   138000   // 32x97 f32 ([k][r], pad 97)             = 12416
#define LDS_TOTAL 150416   // < 160 KiB/CU

__device__ __forceinline__ float sigmoidf_(float x) {
    return 1.0f / (1.0f + __expf(-x));
}
__device__ __forceinline__ unsigned pkrtz(float a, float b) {
    unsigned r;
    asm("v_cvt_pkrtz_f16_f32 %0, %1, %2" : "=v"(r) : "v"(a), "v"(b));
    return r;
}
__device__ __forceinline__ unsigned pk_add(unsigned a, unsigned b) {
    unsigned r;
    asm("v_pk_add_f16 %0, %1, %2" : "=v"(r) : "v"(a), "v"(b));
    return r;
}
__device__ __forceinline__ unsigned pk_fma(unsigned a, unsigned b, unsigned c) {
    unsigned r;
    asm("v_pk_fma_f16 %0, %1, %2, %3" : "=v"(r) : "v"(a), "v"(b), "v"(c));
    return r;
}
__device__ __forceinline__ unsigned pk_relu(unsigned a) {
    unsigned r, z = 0u;
    asm("v_pk_max_f16 %0, %1, %2" : "=v"(r) : "v"(a), "v"(z));
    return r;
}
// 16B L2-bypassing load (agent scope, L3 point read). Results must not be
// consumed until the explicit s_waitcnt below (inline-asm loads are not
// tracked by the compiler's waitcnt insertion).
__device__ __forceinline__ uintx4 load_b128_sc1(const uintx4* p) {
    uintx4 r;
    asm volatile("global_load_dwordx4 %0, %1, off sc1" : "=v"(r) : "v"(p));
    return r;
}

// ---------------------------------------------------------------------------
// Grid barrier v2 — decoupled arrival/release lines so pollers never queue
// in front of arrivals (R4 lesson: 256-way spin on the SAME line as the
// fetch_adds at s_sleep(2) saturates one L3 bank and stretches every phase).
//   arrival: 2-level tree — 8 group counters (bid>>5) on separate 128 B
//            lines -> 1 root counter -> single 'rdy' word (own line).
//   release: pollers read only 'rdy' (read-mostly line), s_sleep(16).
// All ops RELAXED sc1 point-ops at L3; no agent acquire/release FENCES
// (those writeback/invalidate whole L2s: the R2 745 us disaster).
// __syncthreads() before arrival drains vmcnt so this block's sc1 stores
// are at L3 before its count bumps (mechanism verified R3/R4: absmax 0.0).
// ---------------------------------------------------------------------------
__device__ __forceinline__ void grid_bar(unsigned* bar, int bi)
{
    __syncthreads();
    if (threadIdx.x == 0) {
        unsigned* cg = bar + (bi * 16 + ((int)blockIdx.x >> 5)) * 32;
        unsigned old = __hip_atomic_fetch_add(cg, 1u, __ATOMIC_RELAXED,
                                              __HIP_MEMORY_SCOPE_AGENT);
        if (old == 31u) {
            unsigned* cr = bar + (bi * 16 + 8) * 32;
            unsigned o2 = __hip_atomic_fetch_add(cr, 1u, __ATOMIC_RELAXED,
                                                 __HIP_MEMORY_SCOPE_AGENT);
            if (o2 == 7u)
                __hip_atomic_store(bar + 4096, (unsigned)(bi + 1),
                                   __ATOMIC_RELAXED, __HIP_MEMORY_SCOPE_AGENT);
        }
        while (__hip_atomic_load(bar + 4096, __ATOMIC_RELAXED,
                                 __HIP_MEMORY_SCOPE_AGENT) < (unsigned)(bi + 1))
            __builtin_amdgcn_s_sleep(16);
        (void)__hip_atomic_load(bar + 4096, __ATOMIC_ACQUIRE,
                                __HIP_MEMORY_SCOPE_AGENT);
    }
    __syncthreads();
}

// ===========================================================================
// Persistent fused kernel v4. Cross-block state: only hb (5 distinct 64 KB
// buffers; sc1 write-through stores / wide sc1 L3 reads). hj + h + weights
// live in LDS. Normal launch (graph-capturable); 1 block/CU co-residency.
// ===========================================================================
struct FParams {
    const float *J, *b, *mpW1, *mpb1, *mpW2, *mpb2, *mpW3, *mpb3;
    const float *Wih, *Whh, *bih, *bhh;
    const float *rW1, *rb1, *rW2, *rb2, *rW3, *rb3;
    unsigned *hbg;        // 5 x 16384 dwords
    unsigned *bar;        // barrier region (zeroed per launch)
    float *out;
};

__global__ __launch_bounds__(512, 1) void fused4_kernel(FParams p)
{
    extern __shared__ __align__(16) char smem[];
    const int tid  = threadIdx.x;
    const int bid  = blockIdx.x;
    const int lane = tid & 63;
    const int wave = tid >> 6;
    const int nsel = wave >> 2;
    const int nw   = wave & 3;
    const int j    = bid * 2 + nsel;
    const int q    = lane >> 4;
    const int c    = lane & 15;

    char* hbS = smem + OFF_HBS;
    float (*msum)[32]   = (float(*)[32])(smem + OFF_MSUM);
    float (*hPrevS)[32] = (float(*)[32])(smem + OFF_HPREV);
    float (*hS)[32]     = (float(*)[32])(smem + OFF_HS);
    float (*msgS)[32]   = (float(*)[32])(smem + OFF_MSG);
    float (*giS)[96]    = (float(*)[96])(smem + OFF_GI);
    float (*ghS)[96]    = (float(*)[96])(smem + OFF_GH);
    char*  hjL  = smem + OFF_HJ;
    float* w1tL = (float*)(smem + OFF_W1T);   // [d=0..66][cc], pitch 65
    float* wihL = (float*)(smem + OFF_WIH);   // [k=0..63][r], pitch 97
    float* whhL = (float*)(smem + OFF_WHH);   // [k=0..31][r], pitch 97
    char*  m2Lw = smem + OFF_M2L + wave * 2304;

    // ---- one-time: stage per-step weights into LDS ----
    for (int n = tid; n < 64 * 67; n += 512) {
        int cc = n / 67, d = n % 67;
        w1tL[d * 65 + cc] = p.mpW1[n];
    }
    for (int n = tid; n < 96 * 64; n += 512)
        wihL[(n & 63) * 97 + (n >> 6)] = p.Wih[n];
    for (int n = tid; n < 96 * 32; n += 512)
        whhL[(n & 31) * 97 + (n >> 5)] = p.Whh[n];

    // ---- invariant per-lane fragment gathers straight from inputs ----
    f16x8 Aw2[2][4], Aw3[2][2];
    #pragma unroll
    for (int f = 0; f < 2; ++f)
        #pragma unroll
        for (int t4 = 0; t4 < 4; ++t4) {
            const float* src = p.mpW2 + (t4 * 16 + c) * 64 + f * 32 + q * 8;
            floatx4 s0 = *(const floatx4*)(src);
            floatx4 s1 = *(const floatx4*)(src + 4);
            uintx4 u;
            u[0] = pkrtz(s0[0], s0[1]); u[1] = pkrtz(s0[2], s0[3]);
            u[2] = pkrtz(s1[0], s1[1]); u[3] = pkrtz(s1[2], s1[3]);
            Aw2[f][t4] = __builtin_bit_cast(f16x8, u);
        }
    #pragma unroll
    for (int f = 0; f < 2; ++f)
        #pragma unroll
        for (int t2 = 0; t2 < 2; ++t2) {
            const float* src = p.mpW3 + (t2 * 16 + c) * 64 + f * 32 + q * 8;
            floatx4 s0 = *(const floatx4*)(src);
            floatx4 s1 = *(const floatx4*)(src + 4);
            uintx4 u;
            u[0] = pkrtz(s0[0], s0[1]); u[1] = pkrtz(s0[2], s0[3]);
            u[2] = pkrtz(s1[0], s1[1]); u[3] = pkrtz(s1[2], s1[3]);
            Aw3[f][t2] = __builtin_bit_cast(f16x8, u);
        }
    uintx4 wja, wjb;
    #pragma unroll
    for (int i = 0; i < 4; ++i) {
        int r0 = q * 8 + 2 * i;
        wja[i] = pkrtz(p.mpW1[r0 * 67 + 64], p.mpW1[(r0 + 1) * 67 + 64]);
        int r1 = r0 + 32;
        wjb[i] = pkrtz(p.mpW1[r1 * 67 + 64], p.mpW1[(r1 + 1) * 67 + 64]);
    }
    floatx4 b2i[4], b3i[2];
    #pragma unroll
    for (int t4 = 0; t4 < 4; ++t4)
        #pragma unroll
        for (int r = 0; r < 4; ++r) b2i[t4][r] = p.mpb2[t4 * 16 + q * 4 + r];
    #pragma unroll
    for (int t2 = 0; t2 < 2; ++t2)
        #pragma unroll
        for (int r = 0; r < 4; ++r) b3i[t2][r] = p.mpb3[t2 * 16 + q * 4 + r];

    // J column j: one-time strided gather
    const float jA = p.J[((8 * q + nw) * 16 + c) * NN + j];
    const float jB = p.J[((8 * q + 4 + nw) * 16 + c) * NN + j];

    __syncthreads();   // w1tL ready

    // ---- initial projection (h = 0): hb[0] for own 2 nodes + hj -> LDS ----
    if (tid < 128) {
        int node = tid >> 6, cc = tid & 63;
        int jj = bid * 2 + node;
        float bj = p.b[jj];
        float si = bj * w1tL[65 * 65 + cc];
        float sj = bj * w1tL[66 * 65 + cc] + p.mpb1[cc];
        float sip = __shfl(si, lane ^ 1);
        float sjp = __shfl(sj, lane ^ 1);
        if (!(cc & 1)) {
            __hip_atomic_store(&p.hbg[jj * 32 + (cc >> 1)], pkrtz(si, sip),
                               __ATOMIC_RELAXED, __HIP_MEMORY_SCOPE_AGENT);
            *(unsigned*)(hjL + node * 128 + (cc >> 1) * 4) = pkrtz(sj, sjp);
        }
    }
    grid_bar(p.bar, 0);

    // ---------------- 5 fused steps ----------------
    #pragma unroll 1
    for (int t = 0; t < 5; ++t) {
        // ---- stage hb[t] (64 KB) -> LDS via wide sc1 L3 reads ----
        {
            const uintx4* gp = (const uintx4*)(p.hbg + t * 16384);
            uintx4 cr[8];
            #pragma unroll
            for (int k = 0; k < 8; ++k)
                cr[k] = load_b128_sc1(gp + k * 512 + tid);
            asm volatile("s_waitcnt vmcnt(0)" ::: "memory");
            __builtin_amdgcn_sched_barrier(0);
            #pragma unroll
            for (int k = 0; k < 8; ++k) {
                int row = k * 64 + (tid >> 3);
                *(uintx4*)(hbS + row * 144 + (tid & 7) * 16) = cr[k];
            }
        }
        uintx4 hja = *(const uintx4*)(hjL + nsel * 128 + q * 16);
        uintx4 hjb = *(const uintx4*)(hjL + nsel * 128 + 64 + q * 16);
        __syncthreads();

        float accf[2][4];
        #pragma unroll
        for (int t2 = 0; t2 < 2; ++t2)
            #pragma unroll
            for (int r = 0; r < 4; ++r) accf[t2][r] = 0.0f;

        auto edge_group = [&](int G, float Jv) {
            const char* rb = hbS + (G * 16 + c) * 144;
            uintx4 vlo = *(const uintx4*)(rb + q * 16);
            uintx4 vhi = *(const uintx4*)(rb + 64 + q * 16);
            const unsigned Jp = pkrtz(Jv, Jv);

            uintx4 a0u, a1u;
            #pragma unroll
            for (int i = 0; i < 4; ++i) {
                a0u[i] = pk_relu(pk_fma(Jp, wja[i], pk_add(vlo[i], hja[i])));
                a1u[i] = pk_relu(pk_fma(Jp, wjb[i], pk_add(vhi[i], hjb[i])));
            }
            f16x8 B0 = __builtin_bit_cast(f16x8, a0u);
            f16x8 B1 = __builtin_bit_cast(f16x8, a1u);

            floatx4 c1[4];
            #pragma unroll
            for (int t4 = 0; t4 < 4; ++t4) {
                c1[t4] = __builtin_amdgcn_mfma_f32_16x16x32_f16(Aw2[0][t4], B0, b2i[t4], 0, 0, 0);
                c1[t4] = __builtin_amdgcn_mfma_f32_16x16x32_f16(Aw2[1][t4], B1, c1[t4], 0, 0, 0);
            }
            #pragma unroll
            for (int t4 = 0; t4 < 4; ++t4) {
                unsigned p0 = pkrtz(fmaxf(c1[t4][0], 0.f), fmaxf(c1[t4][1], 0.f));
                unsigned p1 = pkrtz(fmaxf(c1[t4][2], 0.f), fmaxf(c1[t4][3], 0.f));
                *(uint2*)(m2Lw + c * 144 + t4 * 32 + q * 8) = make_uint2(p0, p1);
            }
            uintx4 rlo = *(const uintx4*)(m2Lw + c * 144 + q * 16);
            uintx4 rhi = *(const uintx4*)(m2Lw + c * 144 + 64 + q * 16);
            f16x8 B2lo = __builtin_bit_cast(f16x8, rlo);
            f16x8 B2hi = __builtin_bit_cast(f16x8, rhi);

            floatx4 c2[2];
            #pragma unroll
            for (int t2 = 0; t2 < 2; ++t2) {
                c2[t2] = __builtin_amdgcn_mfma_f32_16x16x32_f16(Aw3[0][t2], B2lo, b3i[t2], 0, 0, 0);
                c2[t2] = __builtin_amdgcn_mfma_f32_16x16x32_f16(Aw3[1][t2], B2hi, c2[t2], 0, 0, 0);
            }
            #pragma unroll
            for (int t2 = 0; t2 < 2; ++t2)
                #pragma unroll
                for (int r = 0; r < 4; ++r)
                    accf[t2][r] += fmaxf(c2[t2][r], 0.0f);
        };

        #pragma unroll
        for (int k = 0; k < 4; ++k) {
            edge_group(8 * k + nw,     __shfl(jA, k * 16 + c));
            edge_group(8 * k + 4 + nw, __shfl(jB, k * 16 + c));
        }

        #pragma unroll
        for (int m = 1; m < 16; m <<= 1)
            #pragma unroll
            for (int t2 = 0; t2 < 2; ++t2)
                #pragma unroll
                for (int r = 0; r < 4; ++r)
                    accf[t2][r] += __shfl_xor(accf[t2][r], m);
        if (c == 0) {
            #pragma unroll
            for (int t2 = 0; t2 < 2; ++t2)
                #pragma unroll
                for (int r = 0; r < 4; ++r)
                    msum[wave][t2 * 16 + q * 4 + r] = accf[t2][r];
        }
        __syncthreads();

        if (tid < 64) {
            int node = tid >> 5, d = tid & 31;
            msgS[node][d] = msum[node * 4 + 0][d] + msum[node * 4 + 1][d] +
                            msum[node * 4 + 2][d] + msum[node * 4 + 3][d];
        }
        __syncthreads();

        if (tid < 192) {
            int node = tid / 96, r = tid % 96;
            float a  = p.bih[r];
            float bb = p.bhh[r];
            if (t != 0) {
                #pragma unroll
                for (int k = 0; k < 32; ++k) {
                    float hv = hPrevS[node][k];
                    a  = fmaf(hv, wihL[k * 97 + r], a);
                    bb = fmaf(hv, whhL[k * 97 + r], bb);
                }
            }
            #pragma unroll
            for (int k = 0; k < 32; ++k)
                a = fmaf(msgS[node][k], wihL[(32 + k) * 97 + r], a);
            giS[node][r] = a; ghS[node][r] = bb;
        }
        __syncthreads();

        if (tid < 64) {
            int node = tid >> 5, d = tid & 31;
            float r  = sigmoidf_(giS[node][d] + ghS[node][d]);
            float z  = sigmoidf_(giS[node][32 + d] + ghS[node][32 + d]);
            float ng = tanhf(giS[node][64 + d] + r * ghS[node][64 + d]);
            float hold = (t == 0) ? 0.0f : hPrevS[node][d];
            float hv = (1.0f - z) * ng + z * hold;
            hS[node][d] = hv;
            hPrevS[node][d] = hv;
        }
        __syncthreads();

        if (t < 4) {
            if (tid < 128) {
                int node = tid >> 6, cc = tid & 63;
                int jj = bid * 2 + node;
                float bj = p.b[jj];
                float si = bj * w1tL[65 * 65 + cc];
                float sj = bj * w1tL[66 * 65 + cc] + p.mpb1[cc];
                #pragma unroll
                for (int d = 0; d < 32; ++d) {
                    float hv = hS[node][d];
                    si = fmaf(hv, w1tL[d * 65 + cc], si);
                    sj = fmaf(hv, w1tL[(32 + d) * 65 + cc], sj);
                }
                float sip = __shfl(si, lane ^ 1);
                float sjp = __shfl(sj, lane ^ 1);
                if (!(cc & 1)) {
                    __hip_atomic_store(&p.hbg[(t + 1) * 16384 + jj * 32 + (cc >> 1)],
                                       pkrtz(si, sip),
                                       __ATOMIC_RELAXED, __HIP_MEMORY_SCOPE_AGENT);
                    *(unsigned*)(hjL + node * 128 + (cc >> 1) * 4) = pkrtz(sj, sjp);
                }
            }
            grid_bar(p.bar, t + 1);
        } else {
            if (wave < 2) {
                int node = wave;
                int jj = bid * 2 + node;
                float y1 = p.rb1[lane];
                const floatx4* w1p = (const floatx4*)(p.rW1 + lane * 32);
                #pragma unroll
                for (int kk = 0; kk < 8; ++kk) {
                    floatx4 v = w1p[kk];
                    #pragma unroll
                    for (int i = 0; i < 4; ++i)
                        y1 = fmaf(hS[node][kk * 4 + i], v[i], y1);
                }
                y1 = fmaxf(y1, 0.0f);
                float y2 = p.rb2[lane];
                const floatx4* w2p = (const floatx4*)(p.rW2 + lane * 64);
                #pragma unroll
                for (int kk = 0; kk < 16; ++kk) {
                    floatx4 v = w2p[kk];
                    #pragma unroll
                    for (int i = 0; i < 4; ++i)
                        y2 = fmaf(__shfl(y1, kk * 4 + i), v[i], y2);
                }
                y2 = fmaxf(y2, 0.0f);
                float y3 = (lane < 2) ? p.rb3[lane] : 0.0f;
                #pragma unroll
                for (int k = 0; k < 64; ++k) {
                    float v = __shfl(y2, k);
                    if (lane < 2) y3 = fmaf(v, p.rW3[lane * 64 + k], y3);
                }
                if (lane < 2) p.out[jj * 2 + lane] = sigmoidf_(y3);
            }
        }
    }
}

// ---------------------------------------------------------------------------
extern "C" void kernel_launch(void* const* d_in, const int* in_sizes, int n_in,
                              void* d_out, int out_size, void* d_ws, size_t ws_size,
                              hipStream_t stream)
{
    float* ws = (float*)d_ws;

    const float* J    = (const float*)d_in[0];
    const float* b    = (const float*)d_in[1];
    const float* mpW1 = (const float*)d_in[2];
    const float* mpb1 = (const float*)d_in[3];
    const float* mpW2 = (const float*)d_in[4];
    const float* mpb2 = (const float*)d_in[5];
    const float* mpW3 = (const float*)d_in[6];
    const float* mpb3 = (const float*)d_in[7];
    const float* Wih  = (const float*)d_in[8];
    const float* Whh  = (const float*)d_in[9];
    const float* bih  = (const float*)d_in[10];
    const float* bhh  = (const float*)d_in[11];
    const float* rW1  = (const float*)d_in[12];
    const float* rb1  = (const float*)d_in[13];
    const float* rW2  = (const float*)d_in[14];
    const float* rb2  = (const float*)d_in[15];
    const float* rW3  = (const float*)d_in[16];
    const float* rb3  = (const float*)d_in[17];

    // hb chain (5 x 64 KB) + barrier region, 8 MB into the workspace
    unsigned* hbg = (unsigned*)(ws + 2097152);             // 81920 dwords
    unsigned* bar = (unsigned*)(ws + 2097152 + 81920);     // 32 KB region

    (void)hipFuncSetAttribute((const void*)fused4_kernel,
                              hipFuncAttributeMaxDynamicSharedMemorySize, LDS_TOTAL);

    FParams fp;
    fp.J = J; fp.b = b; fp.mpW1 = mpW1; fp.mpb1 = mpb1; fp.mpW2 = mpW2;
    fp.mpb2 = mpb2; fp.mpW3 = mpW3; fp.mpb3 = mpb3;
    fp.Wih = Wih; fp.Whh = Whh; fp.bih = bih; fp.bhh = bhh;
    fp.rW1 = rW1; fp.rb1 = rb1; fp.rW2 = rW2; fp.rb2 = rb2; fp.rW3 = rW3; fp.rb3 = rb3;
    fp.hbg = hbg; fp.bar = bar;
    fp.out = (float*)d_out;

    // zero the barrier region (counters + rdy word) — required every run
    // (workspace is re-poisoned between runs)
    (void)hipMemsetAsync((void*)bar, 0, 32768, stream);

    fused4_kernel<<<dim3(NB), dim3(512), LDS_TOTAL, stream>>>(fp);
}